// Round 9
// baseline (706.221 us; speedup 1.0000x reference)
//
#include <hip/hip_runtime.h>
#include <stdint.h>

typedef unsigned short u16;
typedef unsigned int u32;
typedef unsigned long long u64;

#define BB 16
#define CC 32
#define NN 512
#define TT 256
#define NT (NN*TT)            // 131072
#define BCNT (BB*CC*NT)       // 67108864
#define ALPHA 0.05f
#define BETAC 0.95f

typedef __attribute__((ext_vector_type(8))) short short8v;
typedef __attribute__((ext_vector_type(4))) float f32x4;

__device__ __forceinline__ float bf2f(u16 u){ return __uint_as_float(((u32)u) << 16); }
__device__ __forceinline__ u16 f2bf(float f){
    u32 b = __float_as_uint(f);
    u32 r = (b + 0x7FFFu + ((b >> 16) & 1u)) >> 16;
    return (u16)r;
}

__device__ __forceinline__ void gload_lds16(const void* g, void* l){
    __builtin_amdgcn_global_load_lds(
        (const __attribute__((address_space(1))) void*)g,
        (__attribute__((address_space(3))) void*)l, 16, 0, 0);
}

// fold (chunk 0..3, col 0..255) onto 16KB LDS: verified round 4 (k4/k6)
__device__ __forceinline__ u32 fold_addr(int chunk, int t){
    int tp = t & 127;
    int cp = chunk + ((t >> 7) << 2);
    int slot = cp ^ (tp & 7) ^ ((tp >> 2) & 7);
    return (u32)((tp * 8 + slot) * 16);
}

// ---------------------------------------------------------------------------
// K0: adj row-normalize -> bf16; bf16 weight prep
__global__ void k0_prep(const float* __restrict__ adj, const float* __restrict__ mlpw,
                        const float* __restrict__ fw, const float* __restrict__ gw,
                        const float* __restrict__ rw,
                        u16* __restrict__ adjb, u16* __restrict__ wcb,
                        u16* __restrict__ fwgb, u16* __restrict__ rwb){
    int i = blockIdx.x;
    int tid = threadIdx.x;
    float a0 = adj[i*NN + tid];
    float a1 = adj[i*NN + tid + 256];
    float s = a0 + a1;
    for (int off = 32; off; off >>= 1) s += __shfl_down(s, off);
    __shared__ float wsum[4];
    if ((tid & 63) == 0) wsum[tid >> 6] = s;
    __syncthreads();
    float inv = 1.0f / (wsum[0] + wsum[1] + wsum[2] + wsum[3] + 1e-8f);
    adjb[i*NN + tid]       = f2bf(a0 * inv);
    adjb[i*NN + tid + 256] = f2bf(a1 * inv);
    if (blockIdx.x == 0){
        for (int idx = tid; idx < 1024; idx += 256){
            int o = idx >> 5, c = idx & 31;
            float m0 = mlpw[o*96 + c];
            float m1 = mlpw[o*96 + 32 + c];
            float m2 = mlpw[o*96 + 64 + c];
            wcb[o*96 + c]      = f2bf(m0 + ALPHA*(m1 + m2));   // Wh
            wcb[o*96 + 32 + c] = f2bf(BETAC*(m1 + ALPHA*m2));  // W1
            wcb[o*96 + 64 + c] = f2bf(BETAC*BETAC*m2);         // W2
        }
        for (int idx = tid; idx < 2048; idx += 256){
            fwgb[idx]        = f2bf(fw[idx]);
            fwgb[2048 + idx] = f2bf(gw[idx]);
        }
        for (int idx = tid; idx < 1024; idx += 256) rwb[idx] = f2bf(rw[idx]);
    }
}

// ---------------------------------------------------------------------------
// K0b: pre-permute 512x512 bf16 into MFMA A-fragment order (round-8 verified).
// frag f = fblk*16 + kc; lane l holds M[fblk*16+(l&15)][kc*32+(l>>4)*8 ..+8)
__global__ void k0b_afrag(const u16* __restrict__ m, u16* __restrict__ mF){
    int f = blockIdx.x;       // 0..511
    int l = threadIdx.x;      // 0..63
    int fblk = f >> 4, kc = f & 15;
    int row = fblk*16 + (l & 15);
    int k   = kc*32 + (l >> 4)*8;
    uint4 v = *(const uint4*)(m + (size_t)row*NN + k);
    *(uint4*)(mF + (size_t)f*512 + l*8) = v;
}

// ---------------------------------------------------------------------------
// K1 (MFMA): [filt;gate][64][t] = W[64x64] · xpair[64][t] per (b,n); h=tanh*sig
__global__ __launch_bounds__(256) void k1_mfma(
    const float* __restrict__ x, const u16* __restrict__ fwgb,
    const float* __restrict__ fb, const float* __restrict__ gb,
    u16* __restrict__ hOut){
    __shared__ __align__(16) float xs[CC][265];
    __shared__ float fbl[CC], gbl[CC];
    const int tid = threadIdx.x;
    const int lane = tid & 63, w = tid >> 6;
    const int g = lane >> 4, c16 = lane & 15;
    const int n = blockIdx.x, b = blockIdx.y;
    if (tid < CC){ fbl[tid] = fb[tid]; gbl[tid] = gb[tid]; }
    const float* xb = x + (size_t)(b*CC)*NT + (size_t)n*TT;
    {
        int c = tid >> 3, l8 = tid & 7;
        #pragma unroll
        for (int i = 0; i < 8; ++i){
            float4 v = *(const float4*)(xb + (size_t)c*NT + i*32 + l8*4);
            *(float4*)&xs[c][i*32 + l8*4] = v;
        }
        if (tid < CC) xs[tid][256] = 0.0f;   // causal zero-pad
    }
    __syncthreads();
    f32x4 acc[4][4];
    #pragma unroll
    for (int mi = 0; mi < 4; ++mi)
        #pragma unroll
        for (int ni = 0; ni < 4; ++ni) acc[mi][ni] = (f32x4){0.f,0.f,0.f,0.f};
    #pragma unroll
    for (int kc = 0; kc < 2; ++kc){
        short8v bfr[4];
        #pragma unroll
        for (int ni = 0; ni < 4; ++ni){
            int t = w*64 + ni*16 + c16;
            union { u16 e[8]; short8v v; } bu;
            #pragma unroll
            for (int i = 0; i < 4; ++i){
                int c = kc*16 + g*4 + i;
                bu.e[2*i]   = f2bf(xs[c][t]);
                bu.e[2*i+1] = f2bf(xs[c][t+1]);
            }
            bfr[ni] = bu.v;
        }
        short8v a[4];
        #pragma unroll
        for (int mi = 0; mi < 4; ++mi)
            a[mi] = *(const short8v*)(fwgb + (mi*16 + c16)*64 + kc*32 + g*8);
        #pragma unroll
        for (int mi = 0; mi < 4; ++mi)
            #pragma unroll
            for (int ni = 0; ni < 4; ++ni)
                acc[mi][ni] = __builtin_amdgcn_mfma_f32_16x16x32_bf16(
                    a[mi], bfr[ni], acc[mi][ni], 0, 0, 0);
    }
    u16* hb = hOut + (size_t)(b*CC)*NT + (size_t)n*TT;
    #pragma unroll
    for (int mi = 0; mi < 2; ++mi)
        #pragma unroll
        for (int r = 0; r < 4; ++r){
            int o = mi*16 + g*4 + r;
            float fbv = fbl[o], gbv = gbl[o];
            #pragma unroll
            for (int ni = 0; ni < 4; ++ni){
                int t = w*64 + ni*16 + c16;
                float fa = acc[mi][ni][r] + fbv;
                float ga = acc[mi+2][ni][r] + gbv;
                float th = 1.0f - 2.0f / (__expf(2.0f*fa) + 1.0f);
                float sg = 1.0f / (1.0f + __expf(-ga));
                hb[(size_t)o*NT + t] = f2bf(th * sg);
            }
        }
}

// ---------------------------------------------------------------------------
// KT1: transpose h [bc][n][t] -> hT [bc][t][n], 64x64 tiles (round-6 verified)
__global__ __launch_bounds__(256) void kT1(const u16* __restrict__ hn, u16* __restrict__ ht){
    __shared__ __align__(16) u16 tile[64][72];
    const int bc = blockIdx.z;
    const int n0 = blockIdx.x * 64;
    const int t0 = blockIdx.y * 64;
    const int tid = threadIdx.x;
    const int r = tid >> 2, cq = tid & 3;
    const u16* src = hn + (size_t)bc*NT + (size_t)(n0 + r)*TT + t0 + cq*16;
    uint4 v0 = *(const uint4*)src;
    uint4 v1 = *(const uint4*)(src + 8);
    *(uint4*)&tile[r][cq*16]     = v0;
    *(uint4*)&tile[r][cq*16 + 8] = v1;
    __syncthreads();
    u16* dst = ht + (size_t)bc*NT + (size_t)(t0 + r)*NN + n0 + cq*16;
    union { u16 e[16]; uint4 q[2]; } o;
    #pragma unroll
    for (int i = 0; i < 16; ++i) o.e[i] = tile[cq*16 + i][r];
    *(uint4*)dst       = o.q[0];
    *(uint4*)(dst + 8) = o.q[1];
}

// ---------------------------------------------------------------------------
// K2m (MFMA, m97-structure): d[bc][i][t] = sum_j adj[i][j] * srcT[bc][t][j]
// Both A (adjF fragment-order) and B (srcT rows, pre-swizzled source) staged
// via global_load_lds width-16; 2 barriers/step; zero VALU repack.
// WRITE_T: additionally emit transposed output dT[bc][t][i] (for next hop).
template<int WRITE_T>
__global__ __launch_bounds__(256) void k2m_mfma(
    const u16* __restrict__ adjF, const u16* __restrict__ srcT,
    u16* __restrict__ d1, u16* __restrict__ dT){
    __shared__ __align__(16) u16 Al[64*128];   // 16 KB: [(fblk_loc*2+kc)*64 + lane] 16B chunks
    __shared__ __align__(16) u16 Bt[128*64];   // 16 KB: [t][slot^] 16B chunks
    const int tid = threadIdx.x;
    const int lane = tid & 63, w = tid >> 6;
    const int wm = w >> 1, wn = w & 1;
    const int g = lane >> 4, c16 = lane & 15;
    // XCD-contiguous mapping (verified round 5)
    const u32 flat = blockIdx.x;                  // 0..4095
    const u32 work = (flat & 7u) * 512u + (flat >> 3);
    const int bc = (int)(work >> 3);
    const int sub = (int)(work & 7u);
    const int it = sub >> 1;
    const int i0 = it * 128;
    const int t0 = (sub & 1) * 128;
    const u16* srcTb = srcT + (size_t)bc * NT;

    // staging source offsets (elements), step-invariant parts
    u32 aoff[4], boff[4];
    #pragma unroll
    for (int q = 0; q < 4; ++q){
        int c = q*256 + tid;
        {   // A: chunk -> (fblk_loc, kc, l)
            int fblk_loc = c >> 7, kc = (c >> 6) & 1, l = c & 63;
            aoff[q] = (u32)(((it*8 + fblk_loc)*16 + kc)*512 + l*8);
        }
        {   // B: chunk -> (t, slot); source k-chunk = slot ^ (t&7)
            int t = c >> 3, slot = c & 7;
            boff[q] = (u32)((t0 + t)*NN + ((slot ^ (t & 7))*8));
        }
    }

    f32x4 acc[4][4];
    #pragma unroll
    for (int mi = 0; mi < 4; ++mi)
        #pragma unroll
        for (int ni = 0; ni < 4; ++ni) acc[mi][ni] = (f32x4){0.f,0.f,0.f,0.f};

    for (int step = 0; step < 8; ++step){
        const int k0 = step * 64;
        __syncthreads();   // previous step's fragment reads complete
        #pragma unroll
        for (int q = 0; q < 4; ++q){
            gload_lds16(adjF  + (size_t)aoff[q] + (size_t)step*1024,
                        (void*)(Al + ((size_t)q*256 + tid)*8));
            gload_lds16(srcTb + (size_t)boff[q] + (size_t)k0,
                        (void*)(Bt + ((size_t)q*256 + tid)*8));
        }
        __syncthreads();   // compiler drains vmcnt(0): staging landed
        #pragma unroll
        for (int kc = 0; kc < 2; ++kc){
            short8v a[4], bfr[4];
            #pragma unroll
            for (int mi = 0; mi < 4; ++mi)
                a[mi] = *(const short8v*)(Al + (((wm*4 + mi)*2 + kc)*64 + lane)*8);
            #pragma unroll
            for (int ni = 0; ni < 4; ++ni){
                int tl = wn*64 + ni*16 + c16;
                bfr[ni] = *(const short8v*)((const char*)Bt
                           + tl*128 + (((kc*4 + g) ^ (tl & 7)) * 16));
            }
            #pragma unroll
            for (int mi = 0; mi < 4; ++mi)
                #pragma unroll
                for (int ni = 0; ni < 4; ++ni)
                    acc[mi][ni] = __builtin_amdgcn_mfma_f32_16x16x32_bf16(
                        a[mi], bfr[ni], acc[mi][ni], 0, 0, 0);
        }
    }

    // epilogue: D col=c16 (t), row=g*4+r (i)  [verified r3]
    u16* e1 = d1 + (size_t)bc * NT;
    #pragma unroll
    for (int mi = 0; mi < 4; ++mi)
        #pragma unroll
        for (int ni = 0; ni < 4; ++ni){
            int tt = t0 + wn*64 + ni*16 + c16;
            int ib = i0 + wm*64 + mi*16 + g*4;
            #pragma unroll
            for (int r = 0; r < 4; ++r)
                e1[(size_t)(ib + r)*TT + tt] = f2bf(acc[mi][ni][r]);
            if (WRITE_T){
                u32 lo = (u32)f2bf(acc[mi][ni][0]) | ((u32)f2bf(acc[mi][ni][1]) << 16);
                u32 hi = (u32)f2bf(acc[mi][ni][2]) | ((u32)f2bf(acc[mi][ni][3]) << 16);
                uint2 qv = {lo, hi};
                *(uint2*)(dT + (size_t)bc*NT + (size_t)tt*NN + ib) = qv;
            }
        }
}

// ---------------------------------------------------------------------------
// K4 (MFMA): y_pre[32][t] = Wc[32x96]·[h;g1;g2][96][t] + mlp_b (round-4/5 proven)
__global__ __launch_bounds__(256) void k4_mfma(
    const u16* __restrict__ h, const u16* __restrict__ g1, const u16* __restrict__ g2,
    const u16* __restrict__ wcb, const float* __restrict__ mlpb,
    u16* __restrict__ ypre, float* __restrict__ psum, float* __restrict__ psq){
    __shared__ __align__(16) u16 Bt[3*8192];       // 48 KB
    __shared__ float mbl[CC];
    __shared__ float part[2][4][CC];
    const int tid = threadIdx.x;
    const int lane = tid & 63, w = tid >> 6;
    const int g = lane >> 4, c16 = lane & 15;
    const int nt0 = blockIdx.x * 256;
    const int b = blockIdx.y;
    const int blk = b * 512 + blockIdx.x;
    if (tid < CC) mbl[tid] = mlpb[tid];
    const size_t boff = (size_t)(b*CC)*NT;
    const u16* srcs[3] = { h + boff, g1 + boff, g2 + boff };
    const int chunk = w, tq = lane;
    #pragma unroll
    for (int s = 0; s < 3; ++s){
        uint2 v[8];
        #pragma unroll
        for (int r = 0; r < 8; ++r)
            v[r] = *(const uint2*)(srcs[s] + (size_t)(chunk*8 + r)*NT + nt0 + tq*4);
        #pragma unroll
        for (int j = 0; j < 4; ++j){
            u32 d[4];
            #pragma unroll
            for (int p = 0; p < 4; ++p){
                u32 lo = (j < 2) ? v[2*p].x   : v[2*p].y;
                u32 hi = (j < 2) ? v[2*p+1].x : v[2*p+1].y;
                u32 sh = (j & 1) * 16;
                d[p] = ((lo >> sh) & 0xFFFFu) | (((hi >> sh) & 0xFFFFu) << 16);
            }
            uint4 q = {d[0], d[1], d[2], d[3]};
            *(uint4*)((char*)Bt + s*16384 + fold_addr(chunk, tq*4 + j)) = q;
        }
    }
    short8v a[3][2];
    #pragma unroll
    for (int s = 0; s < 3; ++s)
        #pragma unroll
        for (int mi = 0; mi < 2; ++mi)
            a[s][mi] = *(const short8v*)(wcb + (mi*16 + c16)*96 + s*32 + g*8);
    f32x4 acc[2][4];
    #pragma unroll
    for (int mi = 0; mi < 2; ++mi)
        #pragma unroll
        for (int ni = 0; ni < 4; ++ni) acc[mi][ni] = (f32x4){0.f,0.f,0.f,0.f};
    __syncthreads();
    #pragma unroll
    for (int s = 0; s < 3; ++s){
        short8v bfr[4];
        #pragma unroll
        for (int ni = 0; ni < 4; ++ni){
            int t = w*64 + ni*16 + c16;
            bfr[ni] = *(const short8v*)((const char*)Bt + s*16384 + fold_addr(g, t));
        }
        #pragma unroll
        for (int mi = 0; mi < 2; ++mi)
            #pragma unroll
            for (int ni = 0; ni < 4; ++ni)
                acc[mi][ni] = __builtin_amdgcn_mfma_f32_16x16x32_bf16(
                    a[s][mi], bfr[ni], acc[mi][ni], 0, 0, 0);
    }
    u16* yb = ypre + boff;
    #pragma unroll
    for (int mi = 0; mi < 2; ++mi)
        #pragma unroll
        for (int r = 0; r < 4; ++r){
            int o = mi*16 + g*4 + r;
            float bias = mbl[o];
            float sv = 0.f, qv = 0.f;
            #pragma unroll
            for (int ni = 0; ni < 4; ++ni){
                int t = nt0 + w*64 + ni*16 + c16;
                float y = acc[mi][ni][r] + bias;
                yb[(size_t)o*NT + t] = f2bf(y);
                sv += y; qv += y*y;
            }
            #pragma unroll
            for (int m = 1; m < 16; m <<= 1){
                sv += __shfl_xor(sv, m);
                qv += __shfl_xor(qv, m);
            }
            if (c16 == 0){ part[0][w][o] = sv; part[1][w][o] = qv; }
        }
    __syncthreads();
    if (tid < CC){
        psum[(size_t)tid*8192 + blk] = part[0][0][tid] + part[0][1][tid] + part[0][2][tid] + part[0][3][tid];
    } else if (tid < 2*CC){
        int o = tid - CC;
        psq[(size_t)o*8192 + blk] = part[1][0][o] + part[1][1][o] + part[1][2][o] + part[1][3][o];
    }
}

// ---------------------------------------------------------------------------
// K5: finalize BN stats -> per-channel scale/shift (deterministic tree)
__global__ void k5_stats(const float* __restrict__ psum, const float* __restrict__ psq,
                         const float* __restrict__ gamma, const float* __restrict__ beta,
                         float* __restrict__ ss){
    int o = blockIdx.x, tid = threadIdx.x;
    double s = 0.0, q = 0.0;
    for (int k = 0; k < 32; ++k){
        s += (double)psum[(size_t)o*8192 + tid + k*256];
        q += (double)psq [(size_t)o*8192 + tid + k*256];
    }
    __shared__ double sd[256], qd[256];
    sd[tid] = s; qd[tid] = q;
    __syncthreads();
    for (int off = 128; off; off >>= 1){
        if (tid < off){ sd[tid] += sd[tid + off]; qd[tid] += qd[tid + off]; }
        __syncthreads();
    }
    if (tid == 0){
        double cnt = (double)BB * NN * TT;
        double mean = sd[0] / cnt;
        double var  = qd[0] / cnt - mean*mean;
        float scale = gamma[o] * (float)(1.0 / sqrt(var + 1e-5));
        float shift = beta[o] - (float)mean * scale;
        ss[o]      = scale;
        ss[CC + o] = shift;
    }
}

// ---------------------------------------------------------------------------
// K6 (MFMA): res = rwb·x; out = relu(res + rb + scale*ypre + shift)
__global__ __launch_bounds__(256) void k6_mfma(
    const float* __restrict__ x, const u16* __restrict__ rwb,
    const float* __restrict__ rb, const float* __restrict__ ss,
    const u16* __restrict__ ypre, float* __restrict__ out){
    __shared__ __align__(16) u16 Bt[8192];   // 16 KB
    __shared__ float rbl[CC], ssl[2*CC];
    const int tid = threadIdx.x;
    const int lane = tid & 63, w = tid >> 6;
    const int g = lane >> 4, c16 = lane & 15;
    const int nt0 = blockIdx.x * 256;
    const int b = blockIdx.y;
    if (tid < CC) rbl[tid] = rb[tid];
    if (tid < 2*CC) ssl[tid] = ss[tid];
    const size_t boff = (size_t)(b*CC)*NT;
    const float* xb = x + boff;
    const int chunk = w, tq = lane;
    {
        float vv[8][4];
        #pragma unroll
        for (int r = 0; r < 8; ++r){
            float4 v = *(const float4*)(xb + (size_t)(chunk*8 + r)*NT + nt0 + tq*4);
            vv[r][0] = v.x; vv[r][1] = v.y; vv[r][2] = v.z; vv[r][3] = v.w;
        }
        #pragma unroll
        for (int j = 0; j < 4; ++j){
            u32 d[4];
            #pragma unroll
            for (int p = 0; p < 4; ++p)
                d[p] = (u32)f2bf(vv[2*p][j]) | ((u32)f2bf(vv[2*p+1][j]) << 16);
            uint4 q = {d[0], d[1], d[2], d[3]};
            *(uint4*)((char*)Bt + fold_addr(chunk, tq*4 + j)) = q;
        }
    }
    short8v a[2];
    #pragma unroll
    for (int mi = 0; mi < 2; ++mi)
        a[mi] = *(const short8v*)(rwb + (mi*16 + c16)*32 + g*8);
    f32x4 acc[2][4];
    #pragma unroll
    for (int mi = 0; mi < 2; ++mi)
        #pragma unroll
        for (int ni = 0; ni < 4; ++ni) acc[mi][ni] = (f32x4){0.f,0.f,0.f,0.f};
    __syncthreads();
    {
        short8v bfr[4];
        #pragma unroll
        for (int ni = 0; ni < 4; ++ni){
            int t = w*64 + ni*16 + c16;
            bfr[ni] = *(const short8v*)((const char*)Bt + fold_addr(g, t));
        }
        #pragma unroll
        for (int mi = 0; mi < 2; ++mi)
            #pragma unroll
            for (int ni = 0; ni < 4; ++ni)
                acc[mi][ni] = __builtin_amdgcn_mfma_f32_16x16x32_bf16(
                    a[mi], bfr[ni], acc[mi][ni], 0, 0, 0);
    }
    const u16* yb = ypre + boff;
    float* ob = out + boff;
    #pragma unroll
    for (int mi = 0; mi < 2; ++mi)
        #pragma unroll
        for (int r = 0; r < 4; ++r){
            int o = mi*16 + g*4 + r;
            float sc = ssl[o], sh = ssl[CC + o], rbv = rbl[o];
            #pragma unroll
            for (int ni = 0; ni < 4; ++ni){
                int t = nt0 + w*64 + ni*16 + c16;
                float v = acc[mi][ni][r] + rbv + sc * bf2f(yb[(size_t)o*NT + t]) + sh;
                ob[(size_t)o*NT + t] = v > 0.0f ? v : 0.0f;
            }
        }
}

// ---------------------------------------------------------------------------
extern "C" void kernel_launch(void* const* d_in, const int* in_sizes, int n_in,
                              void* d_out, int out_size, void* d_ws, size_t ws_size,
                              hipStream_t stream){
    const float* x     = (const float*)d_in[0];
    const float* adj   = (const float*)d_in[1];
    const float* fw    = (const float*)d_in[2];
    const float* fb    = (const float*)d_in[3];
    const float* gw    = (const float*)d_in[4];
    const float* gb    = (const float*)d_in[5];
    const float* mlpw  = (const float*)d_in[6];
    const float* mlpb  = (const float*)d_in[7];
    const float* rw    = (const float*)d_in[8];
    const float* rb    = (const float*)d_in[9];
    const float* gamma = (const float*)d_in[10];
    const float* beta  = (const float*)d_in[11];
    float* out = (float*)d_out;

    char* ws = (char*)d_ws;
    u16*   h_ws  = (u16*)(ws);                          // h (normal); ypre in-place later
    u16*   g1_ws = (u16*)(ws + (size_t)BCNT*2);         // g1 (normal)
    char*  p     = ws + (size_t)BCNT*4;
    u16*   adjb  = (u16*)p;            p += (size_t)NN*NN*2;   // 512 KB
    u16*   adjF  = (u16*)p;            p += (size_t)NN*NN*2;   // 512 KB
    u16*   wcb   = (u16*)p;            p += 3072*2;
    u16*   fwgb  = (u16*)p;            p += 4096*2;
    u16*   rwb   = (u16*)p;            p += 1024*2;
    float* ssb   = (float*)p;          p += 64*4;
    float* psum  = (float*)p;          p += (size_t)CC*8192*4; // 1 MB
    float* psq   = (float*)p;                                  // 1 MB
    // d_out juggling: hT in lo half (dead after k2m#1); g1T in hi half
    // (dead after k2m#2); g2 overwrites hT in lo half (consumed by k4);
    // k6 finally writes the full f32 output.
    u16*   hT    = (u16*)d_out;
    u16*   g1T   = (u16*)d_out + (size_t)BCNT;
    u16*   g2b   = (u16*)d_out;

    k0_prep <<<NN, 256, 0, stream>>>(adj, mlpw, fw, gw, rw, adjb, wcb, fwgb, rwb);
    k0b_afrag<<<512, 64, 0, stream>>>(adjb, adjF);
    k1_mfma <<<dim3(NN, BB), 256, 0, stream>>>(x, fwgb, fb, gb, h_ws);
    kT1     <<<dim3(8, 4, 512), 256, 0, stream>>>(h_ws, hT);
    k2m_mfma<1><<<dim3(4096), 256, 0, stream>>>(adjF, hT,  g1_ws, g1T);
    k2m_mfma<0><<<dim3(4096), 256, 0, stream>>>(adjF, g1T, g2b,   (u16*)nullptr);
    k4_mfma <<<dim3(512, BB), 256, 0, stream>>>(h_ws, g1_ws, g2b, wcb, mlpb,
                                                h_ws, psum, psq);
    k5_stats<<<CC, 256, 0, stream>>>(psum, psq, gamma, beta, ssb);
    k6_mfma <<<dim3(512, BB), 256, 0, stream>>>(x, rwb, rb, ssb, h_ws, out);
}

// Round 10
// 637.681 us; speedup vs baseline: 1.1075x; 1.1075x over previous
//
#include <hip/hip_runtime.h>
#include <stdint.h>

typedef unsigned short u16;
typedef unsigned int u32;
typedef unsigned long long u64;

#define BB 16
#define CC 32
#define NN 512
#define TT 256
#define NT (NN*TT)            // 131072
#define BCNT (BB*CC*NT)       // 67108864
#define ALPHA 0.05f
#define BETAC 0.95f

typedef __attribute__((ext_vector_type(8))) short short8v;
typedef __attribute__((ext_vector_type(4))) float f32x4;

__device__ __forceinline__ float bf2f(u16 u){ return __uint_as_float(((u32)u) << 16); }
__device__ __forceinline__ u16 f2bf(float f){
    u32 b = __float_as_uint(f);
    u32 r = (b + 0x7FFFu + ((b >> 16) & 1u)) >> 16;
    return (u16)r;
}

// k2 B-tile LDS slot fn (verified rounds 3/5/7)
__device__ __forceinline__ u32 bslot_addr(int chunk, int t){
    int slot = chunk ^ (t & 7) ^ ((t >> 2) & 7);
    return (u32)((t * 8 + slot) * 16);
}
// fold (chunk 0..3, col 0..255) onto 16KB LDS: verified round 4 (k6)
__device__ __forceinline__ u32 fold_addr(int chunk, int t){
    int tp = t & 127;
    int cp = chunk + ((t >> 7) << 2);
    int slot = cp ^ (tp & 7) ^ ((tp >> 2) & 7);
    return (u32)((tp * 8 + slot) * 16);
}

// ---------------------------------------------------------------------------
// K0: adj row-normalize -> bf16; bf16 weight prep
__global__ void k0_prep(const float* __restrict__ adj, const float* __restrict__ mlpw,
                        const float* __restrict__ fw, const float* __restrict__ gw,
                        const float* __restrict__ rw,
                        u16* __restrict__ adjb, u16* __restrict__ wcb,
                        u16* __restrict__ fwgb, u16* __restrict__ rwb){
    int i = blockIdx.x;
    int tid = threadIdx.x;
    float a0 = adj[i*NN + tid];
    float a1 = adj[i*NN + tid + 256];
    float s = a0 + a1;
    for (int off = 32; off; off >>= 1) s += __shfl_down(s, off);
    __shared__ float wsum[4];
    if ((tid & 63) == 0) wsum[tid >> 6] = s;
    __syncthreads();
    float inv = 1.0f / (wsum[0] + wsum[1] + wsum[2] + wsum[3] + 1e-8f);
    adjb[i*NN + tid]       = f2bf(a0 * inv);
    adjb[i*NN + tid + 256] = f2bf(a1 * inv);
    if (blockIdx.x == 0){
        for (int idx = tid; idx < 1024; idx += 256){
            int o = idx >> 5, c = idx & 31;
            float m0 = mlpw[o*96 + c];
            float m1 = mlpw[o*96 + 32 + c];
            float m2 = mlpw[o*96 + 64 + c];
            wcb[o*96 + c]      = f2bf(m0 + ALPHA*(m1 + m2));   // Wh
            wcb[o*96 + 32 + c] = f2bf(BETAC*(m1 + ALPHA*m2));  // W1
            wcb[o*96 + 64 + c] = f2bf(BETAC*BETAC*m2);         // W2
        }
        for (int idx = tid; idx < 2048; idx += 256){
            fwgb[idx]        = f2bf(fw[idx]);
            fwgb[2048 + idx] = f2bf(gw[idx]);
        }
        for (int idx = tid; idx < 1024; idx += 256) rwb[idx] = f2bf(rw[idx]);
    }
}

// ---------------------------------------------------------------------------
// K0b: pre-permute 512x512 bf16 into MFMA A-fragment order (r8 verified).
__global__ void k0b_afrag(const u16* __restrict__ m, u16* __restrict__ mF){
    int f = blockIdx.x;       // 0..511
    int l = threadIdx.x;      // 0..63
    int fblk = f >> 4, kc = f & 15;
    int row = fblk*16 + (l & 15);
    int k   = kc*32 + (l >> 4)*8;
    uint4 v = *(const uint4*)(m + (size_t)row*NN + k);
    *(uint4*)(mF + (size_t)f*512 + l*8) = v;
}

// ---------------------------------------------------------------------------
// K0b2: fragment-order the K-concat matrix AA = [A | A2] (512 rows x 1024 K).
// frag f = fblk*32 + kc32, fblk=row/16, kc32 in [0,32).
__global__ void k0b2_aafrag(const u16* __restrict__ adjb, const u16* __restrict__ a2b,
                            u16* __restrict__ AAF){
    int f = blockIdx.x;       // 0..1023
    int l = threadIdx.x;      // 0..63
    int fblk = f >> 5, kc = f & 31;
    int row = fblk*16 + (l & 15);
    int k   = kc*32 + (l >> 4)*8;
    const u16* src = (k < 512) ? (adjb + (size_t)row*NN + k)
                               : (a2b  + (size_t)row*NN + (k - 512));
    uint4 v = *(const uint4*)src;
    *(uint4*)(AAF + (size_t)f*512 + l*8) = v;
}

// ---------------------------------------------------------------------------
// K0c: A2 = adjn * adjn (r8 verified). 128x128 tiles, 16 blocks.
__global__ __launch_bounds__(256) void k0c_a2(
    const u16* __restrict__ adjF, const u16* __restrict__ adjb, u16* __restrict__ a2b){
    __shared__ __align__(16) u16 Bl[128*64];
    const int tid = threadIdx.x;
    const int lane = tid & 63, w = tid >> 6;
    const int wm = w >> 1, wn = w & 1;
    const int g = lane >> 4, c16 = lane & 15;
    const int it = blockIdx.x;
    const int i0 = it * 128;
    const int t0 = blockIdx.y * 128;
    const int s_chunk = tid >> 5;
    const int s_tb    = (tid & 31) * 4;
    f32x4 acc[4][4];
    #pragma unroll
    for (int mi = 0; mi < 4; ++mi)
        #pragma unroll
        for (int ni = 0; ni < 4; ++ni) acc[mi][ni] = (f32x4){0.f,0.f,0.f,0.f};
    const u16* afr[4];
    #pragma unroll
    for (int mi = 0; mi < 4; ++mi)
        afr[mi] = adjF + (size_t)(((it*2 + wm)*4 + mi)*16)*512 + lane*8;
    for (int step = 0; step < 8; ++step){
        const int k0 = step * 64;
        uint2 v[8];
        #pragma unroll
        for (int r = 0; r < 8; ++r)
            v[r] = *(const uint2*)(adjb + (size_t)(k0 + s_chunk*8 + r)*NN + t0 + s_tb);
        __syncthreads();
        #pragma unroll
        for (int j = 0; j < 4; ++j){
            u32 d[4];
            #pragma unroll
            for (int p = 0; p < 4; ++p){
                u32 lo = (j < 2) ? v[2*p].x   : v[2*p].y;
                u32 hi = (j < 2) ? v[2*p+1].x : v[2*p+1].y;
                u32 sh = (j & 1) * 16;
                d[p] = ((lo >> sh) & 0xFFFFu) | (((hi >> sh) & 0xFFFFu) << 16);
            }
            uint4 q = {d[0], d[1], d[2], d[3]};
            *(uint4*)((char*)Bl + bslot_addr(s_chunk, s_tb + j)) = q;
        }
        __syncthreads();
        #pragma unroll
        for (int kc = 0; kc < 2; ++kc){
            const int kc16 = step*2 + kc;
            short8v a[4], bfr[4];
            #pragma unroll
            for (int mi = 0; mi < 4; ++mi)
                a[mi] = *(const short8v*)(afr[mi] + kc16*512);
            #pragma unroll
            for (int ni = 0; ni < 4; ++ni){
                int t_loc = wn*64 + ni*16 + c16;
                bfr[ni] = *(const short8v*)((char*)Bl + bslot_addr(kc*4 + g, t_loc));
            }
            #pragma unroll
            for (int mi = 0; mi < 4; ++mi)
                #pragma unroll
                for (int ni = 0; ni < 4; ++ni)
                    acc[mi][ni] = __builtin_amdgcn_mfma_f32_16x16x32_bf16(
                        a[mi], bfr[ni], acc[mi][ni], 0, 0, 0);
        }
    }
    #pragma unroll
    for (int mi = 0; mi < 4; ++mi)
        #pragma unroll
        for (int ni = 0; ni < 4; ++ni){
            int tt = t0 + wn*64 + ni*16 + c16;
            int ib = i0 + wm*64 + mi*16 + g*4;
            #pragma unroll
            for (int r = 0; r < 4; ++r)
                a2b[(size_t)(ib + r)*NN + tt] = f2bf(acc[mi][ni][r]);
        }
}

// ---------------------------------------------------------------------------
// K1x: gated conv (r7-verbatim conv MFMA) + channel-mixes via LDS bounce:
//   h = tanh(filt)*sig(gate)  (LDS only, never hits HBM)
//   v = W1·h ; u = W2·h ; w = Wh·h + mlpb      (bf16 to global)
__global__ __launch_bounds__(256) void k1x_mfma(
    const float* __restrict__ x, const u16* __restrict__ fwgb,
    const float* __restrict__ fb, const float* __restrict__ gb,
    const u16* __restrict__ wcb, const float* __restrict__ mlpb,
    u16* __restrict__ vO, u16* __restrict__ uO, u16* __restrict__ wO){
    __shared__ __align__(16) float xs[CC][265];
    __shared__ __align__(16) u16 hT[256][40];    // [t][c], stride 80B
    __shared__ float fbl[CC], gbl[CC], mbl[CC];
    const int tid = threadIdx.x;
    const int lane = tid & 63, wv = tid >> 6;
    const int g = lane >> 4, c16 = lane & 15;
    const int n = blockIdx.x, b = blockIdx.y;
    if (tid < CC){ fbl[tid] = fb[tid]; gbl[tid] = gb[tid]; mbl[tid] = mlpb[tid]; }
    const float* xb = x + (size_t)(b*CC)*NT + (size_t)n*TT;
    {
        int c = tid >> 3, l8 = tid & 7;
        #pragma unroll
        for (int i = 0; i < 8; ++i){
            float4 v = *(const float4*)(xb + (size_t)c*NT + i*32 + l8*4);
            *(float4*)&xs[c][i*32 + l8*4] = v;
        }
        if (tid < CC) xs[tid][256] = 0.0f;   // causal zero-pad
    }
    __syncthreads();
    f32x4 acc[4][4];
    #pragma unroll
    for (int mi = 0; mi < 4; ++mi)
        #pragma unroll
        for (int ni = 0; ni < 4; ++ni) acc[mi][ni] = (f32x4){0.f,0.f,0.f,0.f};
    #pragma unroll
    for (int kc = 0; kc < 2; ++kc){
        short8v bfr[4];
        #pragma unroll
        for (int ni = 0; ni < 4; ++ni){
            int t = wv*64 + ni*16 + c16;
            union { u16 e[8]; short8v v; } bu;
            #pragma unroll
            for (int i = 0; i < 4; ++i){
                int c = kc*16 + g*4 + i;
                bu.e[2*i]   = f2bf(xs[c][t]);
                bu.e[2*i+1] = f2bf(xs[c][t+1]);
            }
            bfr[ni] = bu.v;
        }
        short8v a[4];
        #pragma unroll
        for (int mi = 0; mi < 4; ++mi)
            a[mi] = *(const short8v*)(fwgb + (mi*16 + c16)*64 + kc*32 + g*8);
        #pragma unroll
        for (int mi = 0; mi < 4; ++mi)
            #pragma unroll
            for (int ni = 0; ni < 4; ++ni)
                acc[mi][ni] = __builtin_amdgcn_mfma_f32_16x16x32_bf16(
                    a[mi], bfr[ni], acc[mi][ni], 0, 0, 0);
    }
    // h -> LDS [t][c]
    #pragma unroll
    for (int mi = 0; mi < 2; ++mi)
        #pragma unroll
        for (int r = 0; r < 4; ++r){
            int o = mi*16 + g*4 + r;
            float fbv = fbl[o], gbv = gbl[o];
            #pragma unroll
            for (int ni = 0; ni < 4; ++ni){
                int t = wv*64 + ni*16 + c16;
                float fa = acc[mi][ni][r] + fbv;
                float ga = acc[mi+2][ni][r] + gbv;
                float th = 1.0f - 2.0f / (__expf(2.0f*fa) + 1.0f);
                float sg = 1.0f / (1.0f + __expf(-ga));
                hT[t][o] = f2bf(th * sg);
            }
        }
    __syncthreads();
    // channel GEMMs: B-frag (shared by all s) = hT[t][g*8..+8)
    short8v hfr[4];
    #pragma unroll
    for (int ni = 0; ni < 4; ++ni)
        hfr[ni] = *(const short8v*)&hT[wv*64 + ni*16 + c16][g*8];
    u16* dsts[3] = { wO, vO, uO };    // s=0 Wh->w(+bias), s=1 W1->v, s=2 W2->u
    #pragma unroll
    for (int s = 0; s < 3; ++s){
        short8v a[2];
        #pragma unroll
        for (int mi = 0; mi < 2; ++mi)
            a[mi] = *(const short8v*)(wcb + (mi*16 + c16)*96 + s*32 + g*8);
        f32x4 ac2[2][4];
        #pragma unroll
        for (int mi = 0; mi < 2; ++mi)
            #pragma unroll
            for (int ni = 0; ni < 4; ++ni) ac2[mi][ni] = (f32x4){0.f,0.f,0.f,0.f};
        #pragma unroll
        for (int mi = 0; mi < 2; ++mi)
            #pragma unroll
            for (int ni = 0; ni < 4; ++ni)
                ac2[mi][ni] = __builtin_amdgcn_mfma_f32_16x16x32_bf16(
                    a[mi], hfr[ni], ac2[mi][ni], 0, 0, 0);
        u16* db = dsts[s];
        #pragma unroll
        for (int mi = 0; mi < 2; ++mi)
            #pragma unroll
            for (int r = 0; r < 4; ++r){
                int o = mi*16 + g*4 + r;
                float bias = (s == 0) ? mbl[o] : 0.0f;
                #pragma unroll
                for (int ni = 0; ni < 4; ++ni){
                    int t = wv*64 + ni*16 + c16;
                    db[(size_t)(b*CC + o)*NT + (size_t)n*TT + t] =
                        f2bf(ac2[mi][ni][r] + bias);
                }
            }
    }
}

// ---------------------------------------------------------------------------
// K2x (MFMA): ypre[bc][i][t] = sum_j AA[i][j]*[v;u][bc][j][t] + w[bc][i][t]
// K=1024 (16 steps), r7-proven repack+dbuf loop, AAF fragment-order A,
// XCD swizzle; epilogue writes ypre bf16 + per-block BN partials.
__global__ __launch_bounds__(256) void k2x_mfma(
    const u16* __restrict__ AAF, const u16* __restrict__ v_, const u16* __restrict__ u_,
    const u16* __restrict__ w_, u16* __restrict__ ypre,
    float* __restrict__ psum, float* __restrict__ psq){
    __shared__ __align__(16) u16 Bl[2][128*64];   // 2 x 16 KB
    __shared__ float ps[4], qs[4];
    const int tid = threadIdx.x;
    const int lane = tid & 63, wv = tid >> 6;
    const int wm = wv >> 1, wn = wv & 1;
    const int g = lane >> 4, c16 = lane & 15;
    const u32 flat = blockIdx.x;                  // 0..4095
    const u32 work = (flat & 7u) * 512u + (flat >> 3);
    const int bc = (int)(work >> 3);
    const int sub = (int)(work & 7u);
    const int it = sub >> 1;
    const int i0 = it * 128;
    const int t0 = (sub & 1) * 128;
    const u16* vb = v_ + (size_t)bc * NT;
    const u16* ub = u_ + (size_t)bc * NT;
    const int s_chunk = tid >> 5;
    const int s_tb    = (tid & 31) * 4;
    f32x4 acc[4][4];
    #pragma unroll
    for (int mi = 0; mi < 4; ++mi)
        #pragma unroll
        for (int ni = 0; ni < 4; ++ni) acc[mi][ni] = (f32x4){0.f,0.f,0.f,0.f};
    // A-fragment pointers: frag = fblk*32 + kc16, fblk = i0/16 + wm*4 + mi
    const u16* afr[4];
    #pragma unroll
    for (int mi = 0; mi < 4; ++mi)
        afr[mi] = AAF + (size_t)((i0 >> 4) + wm*4 + mi)*32*512 + lane*8;

    // prologue: load step 0 (rows 0..63 of v)
    uint2 vv[8];
    #pragma unroll
    for (int r = 0; r < 8; ++r)
        vv[r] = *(const uint2*)(vb + (size_t)(s_chunk*8 + r)*TT + t0 + s_tb);

    for (int step = 0; step < 16; ++step){
        char* bbase = (char*)Bl + (size_t)(step & 1) * 16384;
        #pragma unroll
        for (int j = 0; j < 4; ++j){
            u32 d[4];
            #pragma unroll
            for (int p = 0; p < 4; ++p){
                u32 lo = (j < 2) ? vv[2*p].x   : vv[2*p].y;
                u32 hi = (j < 2) ? vv[2*p+1].x : vv[2*p+1].y;
                u32 sh = (j & 1) * 16;
                d[p] = ((lo >> sh) & 0xFFFFu) | (((hi >> sh) & 0xFFFFu) << 16);
            }
            uint4 q = {d[0], d[1], d[2], d[3]};
            *(uint4*)(bbase + bslot_addr(s_chunk, s_tb + j)) = q;
        }
        if (step < 15){
            const u16* base = (step + 1 < 8) ? vb : ub;
            const int row0 = ((step + 1) * 64) & 511;
            #pragma unroll
            for (int r = 0; r < 8; ++r)
                vv[r] = *(const uint2*)(base + (size_t)(row0 + s_chunk*8 + r)*TT + t0 + s_tb);
        }
        __syncthreads();
        #pragma unroll
        for (int kc = 0; kc < 2; ++kc){
            const int kc16 = step*2 + kc;
            short8v a[4], bfr[4];
            #pragma unroll
            for (int mi = 0; mi < 4; ++mi)
                a[mi] = *(const short8v*)(afr[mi] + kc16*512);
            #pragma unroll
            for (int ni = 0; ni < 4; ++ni){
                int t_loc = wn*64 + ni*16 + c16;
                bfr[ni] = *(const short8v*)(bbase + bslot_addr(kc*4 + g, t_loc));
            }
            #pragma unroll
            for (int mi = 0; mi < 4; ++mi)
                #pragma unroll
                for (int ni = 0; ni < 4; ++ni)
                    acc[mi][ni] = __builtin_amdgcn_mfma_f32_16x16x32_bf16(
                        a[mi], bfr[ni], acc[mi][ni], 0, 0, 0);
        }
    }
    // epilogue: + w, write ypre, BN partials
    const u16* wb = w_ + (size_t)bc * NT;
    u16* yb = ypre + (size_t)bc * NT;
    float sv = 0.f, qv = 0.f;
    #pragma unroll
    for (int mi = 0; mi < 4; ++mi)
        #pragma unroll
        for (int ni = 0; ni < 4; ++ni){
            int tt = t0 + wn*64 + ni*16 + c16;
            int ib = i0 + wm*64 + mi*16 + g*4;
            #pragma unroll
            for (int r = 0; r < 4; ++r){
                size_t idx = (size_t)(ib + r)*TT + tt;
                float y = acc[mi][ni][r] + bf2f(wb[idx]);
                yb[idx] = f2bf(y);
                sv += y; qv += y*y;
            }
        }
    #pragma unroll
    for (int off = 32; off; off >>= 1){
        sv += __shfl_xor(sv, off);
        qv += __shfl_xor(qv, off);
    }
    if (lane == 0){ ps[wv] = sv; qs[wv] = qv; }
    __syncthreads();
    if (tid == 0){
        psum[work] = ps[0] + ps[1] + ps[2] + ps[3];
        psq[work]  = qs[0] + qs[1] + qs[2] + qs[3];
    }
}

// ---------------------------------------------------------------------------
// K5: finalize BN stats (128 partials per channel: 16 b x 8 sub-blocks)
__global__ void k5_stats(const float* __restrict__ psum, const float* __restrict__ psq,
                         const float* __restrict__ gamma, const float* __restrict__ beta,
                         float* __restrict__ ss){
    int o = blockIdx.x, tid = threadIdx.x;
    double s = 0.0, q = 0.0;
    if (tid < 128){
        int b = tid >> 3, sub = tid & 7;
        int idx = (((b*CC + o) << 3) | sub);
        s = (double)psum[idx];
        q = (double)psq[idx];
    }
    __shared__ double sd[256], qd[256];
    sd[tid] = s; qd[tid] = q;
    __syncthreads();
    for (int off = 128; off; off >>= 1){
        if (tid < off){ sd[tid] += sd[tid + off]; qd[tid] += qd[tid + off]; }
        __syncthreads();
    }
    if (tid == 0){
        double cnt = (double)BB * NN * TT;
        double mean = sd[0] / cnt;
        double var  = qd[0] / cnt - mean*mean;
        float scale = gamma[o] * (float)(1.0 / sqrt(var + 1e-5));
        float shift = beta[o] - (float)mean * scale;
        ss[o]      = scale;
        ss[CC + o] = shift;
    }
}

// ---------------------------------------------------------------------------
// K6 (MFMA): res = rwb·x; out = relu(res + rb + scale*ypre + shift)
__global__ __launch_bounds__(256) void k6_mfma(
    const float* __restrict__ x, const u16* __restrict__ rwb,
    const float* __restrict__ rb, const float* __restrict__ ss,
    const u16* __restrict__ ypre, float* __restrict__ out){
    __shared__ __align__(16) u16 Bt[8192];   // 16 KB
    __shared__ float rbl[CC], ssl[2*CC];
    const int tid = threadIdx.x;
    const int lane = tid & 63, w = tid >> 6;
    const int g = lane >> 4, c16 = lane & 15;
    const int nt0 = blockIdx.x * 256;
    const int b = blockIdx.y;
    if (tid < CC) rbl[tid] = rb[tid];
    if (tid < 2*CC) ssl[tid] = ss[tid];
    const size_t boff = (size_t)(b*CC)*NT;
    const float* xb = x + boff;
    const int chunk = w, tq = lane;
    {
        float vv[8][4];
        #pragma unroll
        for (int r = 0; r < 8; ++r){
            float4 v = *(const float4*)(xb + (size_t)(chunk*8 + r)*NT + nt0 + tq*4);
            vv[r][0] = v.x; vv[r][1] = v.y; vv[r][2] = v.z; vv[r][3] = v.w;
        }
        #pragma unroll
        for (int j = 0; j < 4; ++j){
            u32 d[4];
            #pragma unroll
            for (int p = 0; p < 4; ++p)
                d[p] = (u32)f2bf(vv[2*p][j]) | ((u32)f2bf(vv[2*p+1][j]) << 16);
            uint4 q = {d[0], d[1], d[2], d[3]};
            *(uint4*)((char*)Bt + fold_addr(chunk, tq*4 + j)) = q;
        }
    }
    short8v a[2];
    #pragma unroll
    for (int mi = 0; mi < 2; ++mi)
        a[mi] = *(const short8v*)(rwb + (mi*16 + c16)*32 + g*8);
    f32x4 acc[2][4];
    #pragma unroll
    for (int mi = 0; mi < 2; ++mi)
        #pragma unroll
        for (int ni = 0; ni < 4; ++ni) acc[mi][ni] = (f32x4){0.f,0.f,0.f,0.f};
    __syncthreads();
    {
        short8v bfr[4];
        #pragma unroll
        for (int ni = 0; ni < 4; ++ni){
            int t = w*64 + ni*16 + c16;
            bfr[ni] = *(const short8v*)((const char*)Bt + fold_addr(g, t));
        }
        #pragma unroll
        for (int mi = 0; mi < 2; ++mi)
            #pragma unroll
            for (int ni = 0; ni < 4; ++ni)
                acc[mi][ni] = __builtin_amdgcn_mfma_f32_16x16x32_bf16(
                    a[mi], bfr[ni], acc[mi][ni], 0, 0, 0);
    }
    const u16* yb = ypre + boff;
    float* ob = out + boff;
    #pragma unroll
    for (int mi = 0; mi < 2; ++mi)
        #pragma unroll
        for (int r = 0; r < 4; ++r){
            int o = mi*16 + g*4 + r;
            float sc = ssl[o], sh = ssl[CC + o], rbv = rbl[o];
            #pragma unroll
            for (int ni = 0; ni < 4; ++ni){
                int t = nt0 + w*64 + ni*16 + c16;
                float v = acc[mi][ni][r] + rbv + sc * bf2f(yb[(size_t)o*NT + t]) + sh;
                ob[(size_t)o*NT + t] = v > 0.0f ? v : 0.0f;
            }
        }
}

// ---------------------------------------------------------------------------
extern "C" void kernel_launch(void* const* d_in, const int* in_sizes, int n_in,
                              void* d_out, int out_size, void* d_ws, size_t ws_size,
                              hipStream_t stream){
    const float* x     = (const float*)d_in[0];
    const float* adj   = (const float*)d_in[1];
    const float* fw    = (const float*)d_in[2];
    const float* fb    = (const float*)d_in[3];
    const float* gw    = (const float*)d_in[4];
    const float* gb    = (const float*)d_in[5];
    const float* mlpw  = (const float*)d_in[6];
    const float* mlpb  = (const float*)d_in[7];
    const float* rw    = (const float*)d_in[8];
    const float* rb    = (const float*)d_in[9];
    const float* gamma = (const float*)d_in[10];
    const float* beta  = (const float*)d_in[11];
    float* out = (float*)d_out;

    char* ws = (char*)d_ws;
    u16*   vbuf  = (u16*)(ws);                          // v  (134 MB)
    u16*   ypre  = (u16*)(ws + (size_t)BCNT*2);         // ypre (134 MB)
    char*  p     = ws + (size_t)BCNT*4;                 // tail (<= ~4 MB, proven)
    u16*   adjb  = (u16*)p;            p += (size_t)NN*NN*2;     // 512 KB
    u16*   adjF  = (u16*)p;            p += (size_t)NN*NN*2;     // 512 KB
    u16*   a2b   = (u16*)p;            p += (size_t)NN*NN*2;     // 512 KB
    u16*   AAF   = (u16*)p;            p += (size_t)NN*NN*2*2;   // 1 MB
    u16*   wcb   = (u16*)p;            p += 3072*2;
    u16*   fwgb  = (u16*)p;            p += 4096*2;
    u16*   rwb   = (u16*)p;            p += 1024*2;
    float* ssb   = (float*)p;          p += 64*4;
    float* psum  = (float*)p;          p += 4096*4;              // 16 KB
    float* psq   = (float*)p;                                    // 16 KB
    // d_out juggling: u in lo half, w in hi half (both dead before k6 writes)
    u16*   ubuf  = (u16*)d_out;
    u16*   wbuf  = (u16*)d_out + (size_t)BCNT;

    k0_prep  <<<NN, 256, 0, stream>>>(adj, mlpw, fw, gw, rw, adjb, wcb, fwgb, rwb);
    k0b_afrag<<<512, 64, 0, stream>>>(adjb, adjF);
    k0c_a2   <<<dim3(4, 4), 256, 0, stream>>>(adjF, adjb, a2b);
    k0b2_aafrag<<<1024, 64, 0, stream>>>(adjb, a2b, AAF);
    k1x_mfma <<<dim3(NN, BB), 256, 0, stream>>>(x, fwgb, fb, gb, wcb, mlpb,
                                                vbuf, ubuf, wbuf);
    k2x_mfma <<<dim3(4096), 256, 0, stream>>>(AAF, vbuf, ubuf, wbuf, ypre, psum, psq);
    k5_stats <<<CC, 256, 0, stream>>>(psum, psq, gamma, beta, ssb);
    k6_mfma  <<<dim3(512, BB), 256, 0, stream>>>(x, rwb, rb, ssb, ypre, out);
}